// Round 1
// baseline (1335.275 us; speedup 1.0000x reference)
//
#include <hip/hip_runtime.h>
#include <math.h>

#define HID 64

static inline size_t align256(size_t x) { return (x + 255) & ~(size_t)255; }

// ---------- graph preprocessing ----------

__global__ void count_dst_kernel(const int* __restrict__ dst, int* __restrict__ cnt, int E) {
  int e = blockIdx.x * blockDim.x + threadIdx.x;
  if (e < E) atomicAdd(&cnt[dst[e]], 1);
}

__global__ void dinv_kernel(const int* __restrict__ cnt, float* __restrict__ dinv, int N) {
  int i = blockIdx.x * blockDim.x + threadIdx.x;
  if (i < N) dinv[i] = rsqrtf((float)(cnt[i] + 1));  // +1 for self-loop; deg >= 1 always
}

// single-block exclusive scan of cnt[0..N) -> rowptr[0..N], cursor copy
__global__ __launch_bounds__(1024) void scan_kernel(const int* __restrict__ cnt,
                                                    int* __restrict__ rowptr,
                                                    int* __restrict__ cursor, int N) {
  __shared__ int part[1024];
  int t = threadIdx.x;
  int chunk = (N + 1023) >> 10;
  int b = t * chunk;
  int e = min(b + chunk, N);
  int s = 0;
  for (int i = b; i < e; ++i) s += cnt[i];
  part[t] = s;
  __syncthreads();
  for (int off = 1; off < 1024; off <<= 1) {
    int v = (t >= off) ? part[t - off] : 0;
    __syncthreads();
    part[t] += v;
    __syncthreads();
  }
  int run = (t == 0) ? 0 : part[t - 1];
  for (int i = b; i < e; ++i) {
    rowptr[i] = run;
    cursor[i] = run;
    run += cnt[i];
  }
  if (t == 0) rowptr[N] = part[1023];
}

__global__ void scatter_kernel(const int* __restrict__ src, const int* __restrict__ dst,
                               const float* __restrict__ dinv, int* __restrict__ cursor,
                               int* __restrict__ colidx, float* __restrict__ wnorm, int E) {
  int e = blockIdx.x * blockDim.x + threadIdx.x;
  if (e >= E) return;
  int s = src[e], d = dst[e];
  int pos = atomicAdd(&cursor[d], 1);
  colidx[pos] = s;
  wnorm[pos] = dinv[s] * dinv[d];
}

// ---------- GEMM: out[N,64] = x[N,K] @ W[K,64] (no bias; bias fused into agg) ----------
// W staged in LDS (K*64*4 B). One wave computes 4 rows; lane = output column.

template <int K>
__global__ __launch_bounds__(256) void gemm_kernel(const float* __restrict__ x,
                                                   const float* __restrict__ W,
                                                   float* __restrict__ out, int N) {
  __shared__ float Ws[K * HID];
  for (int i = threadIdx.x; i < K * HID / 4; i += 256)
    ((float4*)Ws)[i] = ((const float4*)W)[i];
  __syncthreads();
  int wv = blockIdx.x * 4 + (threadIdx.x >> 6);
  int lane = threadIdx.x & 63;
  int row0 = wv * 4;
  if (row0 >= N) return;
  const float* x0 = x + (size_t)row0 * K;
  const float* x1 = x0 + ((row0 + 1 < N) ? K : 0);
  const float* x2 = x0 + ((row0 + 2 < N) ? 2 * K : 0);
  const float* x3 = x0 + ((row0 + 3 < N) ? 3 * K : 0);
  float a0 = 0.f, a1 = 0.f, a2 = 0.f, a3 = 0.f;
#pragma unroll 4
  for (int k = 0; k < K; k += 4) {
    float w0 = Ws[(k + 0) * HID + lane];
    float w1 = Ws[(k + 1) * HID + lane];
    float w2 = Ws[(k + 2) * HID + lane];
    float w3 = Ws[(k + 3) * HID + lane];
    float4 p = *(const float4*)(x0 + k);
    float4 q = *(const float4*)(x1 + k);
    float4 r = *(const float4*)(x2 + k);
    float4 u = *(const float4*)(x3 + k);
    a0 = fmaf(p.w, w3, fmaf(p.z, w2, fmaf(p.y, w1, fmaf(p.x, w0, a0))));
    a1 = fmaf(q.w, w3, fmaf(q.z, w2, fmaf(q.y, w1, fmaf(q.x, w0, a1))));
    a2 = fmaf(r.w, w3, fmaf(r.z, w2, fmaf(r.y, w1, fmaf(r.x, w0, a2))));
    a3 = fmaf(u.w, w3, fmaf(u.z, w2, fmaf(u.y, w1, fmaf(u.x, w0, a3))));
  }
  size_t o = (size_t)row0 * HID + lane;
  out[o] = a0;
  if (row0 + 1 < N) out[o + HID] = a1;
  if (row0 + 2 < N) out[o + 2 * HID] = a2;
  if (row0 + 3 < N) out[o + 3 * HID] = a3;
}

// ---------- fused aggregation: out[d] = sum_{e: dst=d} norm_e * h[src_e] + dinv[d]^2*h[d] + b
//            (+ optional relu + L2 row-normalize). One wave per node, lane = feature. ----------

template <bool RELU_NORM>
__global__ void agg_kernel(const int* __restrict__ rowptr, const int* __restrict__ colidx,
                           const float* __restrict__ wnorm, const float* __restrict__ dinv,
                           const float* __restrict__ h, const float* __restrict__ bias,
                           float* __restrict__ out, int N) {
  int wv = (blockIdx.x * blockDim.x + threadIdx.x) >> 6;
  int lane = threadIdx.x & 63;
  if (wv >= N) return;
  int beg = rowptr[wv];
  int end = rowptr[wv + 1];
  float di = dinv[wv];
  float acc = di * di * h[(size_t)wv * HID + lane] + bias[lane];
  for (int j = beg; j < end; ++j) {
    int s = colidx[j];
    float w = wnorm[j];
    acc = fmaf(w, h[(size_t)s * HID + lane], acc);
  }
  size_t o = (size_t)wv * HID + lane;
  if (RELU_NORM) {
    float v = fmaxf(acc, 0.f);
    float ss = v * v;
#pragma unroll
    for (int off = 32; off; off >>= 1) ss += __shfl_xor(ss, off, 64);
    out[o] = v / fmaxf(sqrtf(ss), 1e-12f);
  } else {
    out[o] = acc;
  }
}

// ---------- atomic fallback path (used only if ws too small for CSR) ----------

__global__ void init_agg_kernel(const float* __restrict__ dinv, const float* __restrict__ h,
                                const float* __restrict__ bias, float* __restrict__ out, int N) {
  int t = blockIdx.x * blockDim.x + threadIdx.x;
  int i = t >> 6, f = t & 63;
  if (i >= N) return;
  float di = dinv[i];
  out[t] = di * di * h[t] + bias[f];
}

__global__ void edge_atomic_kernel(const int* __restrict__ src, const int* __restrict__ dst,
                                   const float* __restrict__ dinv, const float* __restrict__ h,
                                   float* __restrict__ out, int E) {
  int t = blockIdx.x * blockDim.x + threadIdx.x;
  int e = t >> 6;
  if (e >= E) return;
  int f = t & 63;
  int s = src[e], d = dst[e];
  atomicAdd(&out[(size_t)d * HID + f], dinv[s] * dinv[d] * h[(size_t)s * HID + f]);
}

__global__ void relu_norm_kernel(float* __restrict__ hbuf, int N) {
  int t = blockIdx.x * blockDim.x + threadIdx.x;
  int i = t >> 6;
  if (i >= N) return;
  float v = fmaxf(hbuf[t], 0.f);
  float ss = v * v;
#pragma unroll
  for (int off = 32; off; off >>= 1) ss += __shfl_xor(ss, off, 64);
  hbuf[t] = v / fmaxf(sqrtf(ss), 1e-12f);
}

// ---------- host ----------

extern "C" void kernel_launch(void* const* d_in, const int* in_sizes, int n_in,
                              void* d_out, int out_size, void* d_ws, size_t ws_size,
                              hipStream_t stream) {
  const float* x  = (const float*)d_in[0];
  const int*   ei = (const int*)d_in[1];
  const float* W1 = (const float*)d_in[2];
  const float* b1 = (const float*)d_in[3];
  const float* W2 = (const float*)d_in[4];
  const float* b2 = (const float*)d_in[5];
  const float* W3 = (const float*)d_in[6];
  const float* b3 = (const float*)d_in[7];
  float* out = (float*)d_out;

  const int IN = in_sizes[2] / HID;   // 256
  const int N  = in_sizes[0] / IN;    // 100000
  const int E  = in_sizes[1] / 2;     // 1600000
  const int* srcI = ei;
  const int* dstI = ei + E;

  char* w = (char*)d_ws;
  size_t off = 0;
  auto alloc = [&](size_t bytes) { void* p = w + off; off = align256(off + bytes); return p; };
  float* A     = (float*)alloc((size_t)N * HID * 4);  // transformed-h scratch
  float* dinv  = (float*)alloc((size_t)N * 4);
  int*   cnt   = (int*)alloc((size_t)N * 4);
  size_t base_need = off;
  int*   rowptr = (int*)alloc((size_t)(N + 1) * 4);
  int*   cursor = (int*)alloc((size_t)N * 4);
  int*   colidx = (int*)alloc((size_t)E * 4);
  float* wnorm  = (float*)alloc((size_t)E * 4);
  size_t csr_need = off;

  if (base_need > ws_size) return;  // cannot run at all
  const bool use_csr = (csr_need <= ws_size);

  const int blkE    = (E + 255) / 256;
  const int blkN    = (N + 255) / 256;
  const int blkRow  = (N + 15) / 16;          // gemm: 4 waves/block * 4 rows/wave
  const int blkWave = (N * 64 + 255) / 256;   // wave-per-node kernels
  const int blkEF   = ((size_t)E * 64 + 255) / 256;

  hipMemsetAsync(cnt, 0, (size_t)N * 4, stream);
  count_dst_kernel<<<blkE, 256, 0, stream>>>(dstI, cnt, E);
  dinv_kernel<<<blkN, 256, 0, stream>>>(cnt, dinv, N);

  if (use_csr) {
    scan_kernel<<<1, 1024, 0, stream>>>(cnt, rowptr, cursor, N);
    scatter_kernel<<<blkE, 256, 0, stream>>>(srcI, dstI, dinv, cursor, colidx, wnorm, E);

    // layer 1: x @ W1 -> A ; agg(A) + b1 -> relu+l2norm -> out (h1)
    gemm_kernel<256><<<blkRow, 256, 0, stream>>>(x, W1, A, N);
    agg_kernel<true><<<blkWave, 256, 0, stream>>>(rowptr, colidx, wnorm, dinv, A, b1, out, N);
    // layer 2: out(h1) @ W2 -> A ; agg -> out (h2)
    gemm_kernel<64><<<blkRow, 256, 0, stream>>>(out, W2, A, N);
    agg_kernel<true><<<blkWave, 256, 0, stream>>>(rowptr, colidx, wnorm, dinv, A, b2, out, N);
    // layer 3: out(h2) @ W3 -> A ; agg (no relu/norm) -> out
    gemm_kernel<64><<<blkRow, 256, 0, stream>>>(out, W3, A, N);
    agg_kernel<false><<<blkWave, 256, 0, stream>>>(rowptr, colidx, wnorm, dinv, A, b3, out, N);
  } else {
    // atomic fallback
    gemm_kernel<256><<<blkRow, 256, 0, stream>>>(x, W1, A, N);
    init_agg_kernel<<<blkWave, 256, 0, stream>>>(dinv, A, b1, out, N);
    edge_atomic_kernel<<<blkEF, 256, 0, stream>>>(srcI, dstI, dinv, A, out, E);
    relu_norm_kernel<<<blkWave, 256, 0, stream>>>(out, N);

    gemm_kernel<64><<<blkRow, 256, 0, stream>>>(out, W2, A, N);
    init_agg_kernel<<<blkWave, 256, 0, stream>>>(dinv, A, b2, out, N);
    edge_atomic_kernel<<<blkEF, 256, 0, stream>>>(srcI, dstI, dinv, A, out, E);
    relu_norm_kernel<<<blkWave, 256, 0, stream>>>(out, N);

    gemm_kernel<64><<<blkRow, 256, 0, stream>>>(out, W3, A, N);
    init_agg_kernel<<<blkWave, 256, 0, stream>>>(dinv, A, b3, out, N);
    edge_atomic_kernel<<<blkEF, 256, 0, stream>>>(srcI, dstI, dinv, A, out, E);
  }
}

// Round 2
// 1057.776 us; speedup vs baseline: 1.2623x; 1.2623x over previous
//
#include <hip/hip_runtime.h>
#include <math.h>

#define HID 64

static inline size_t align256(size_t x) { return (x + 255) & ~(size_t)255; }

// ---------- graph preprocessing ----------

__global__ void count_dst_kernel(const int* __restrict__ dst, int* __restrict__ cnt, int E) {
  int e = blockIdx.x * blockDim.x + threadIdx.x;
  if (e < E) atomicAdd(&cnt[dst[e]], 1);
}

__global__ void dinv_kernel(const int* __restrict__ cnt, float* __restrict__ dinv, int N) {
  int i = blockIdx.x * blockDim.x + threadIdx.x;
  if (i < N) dinv[i] = rsqrtf((float)(cnt[i] + 1));  // +1 self-loop; deg >= 1 always
}

// single-block exclusive scan of cnt[0..N) -> rowptr[0..N], cursor copy
__global__ __launch_bounds__(1024) void scan_kernel(const int* __restrict__ cnt,
                                                    int* __restrict__ rowptr,
                                                    int* __restrict__ cursor, int N) {
  __shared__ int part[1024];
  int t = threadIdx.x;
  int chunk = (N + 1023) >> 10;
  int b = t * chunk;
  int e = min(b + chunk, N);
  int s = 0;
  for (int i = b; i < e; ++i) s += cnt[i];
  part[t] = s;
  __syncthreads();
  for (int off = 1; off < 1024; off <<= 1) {
    int v = (t >= off) ? part[t - off] : 0;
    __syncthreads();
    part[t] += v;
    __syncthreads();
  }
  int run = (t == 0) ? 0 : part[t - 1];
  for (int i = b; i < e; ++i) {
    rowptr[i] = run;
    cursor[i] = run;
    run += cnt[i];
  }
  if (t == 0) rowptr[N] = part[1023];
}

// pack (src, norm) into one int2 per edge, dst-sorted via cursor
__global__ void scatter_kernel(const int* __restrict__ src, const int* __restrict__ dst,
                               const float* __restrict__ dinv, int* __restrict__ cursor,
                               int2* __restrict__ epack, int E) {
  int e = blockIdx.x * blockDim.x + threadIdx.x;
  if (e >= E) return;
  int s = src[e], d = dst[e];
  int pos = atomicAdd(&cursor[d], 1);
  epack[pos] = make_int2(s, __float_as_int(dinv[s] * dinv[d]));
}

// ---------- GEMM: out[N,64] = x[N,K] @ W[K,64] (bias fused into agg) ----------
// K-tiled: 16 KB LDS chunk of W as float4[kb][col]; 8 rows/wave; lane = col.

template <int K>
__global__ __launch_bounds__(256, 4) void gemm_kernel(const float* __restrict__ x,
                                                      const float* __restrict__ W,
                                                      float* __restrict__ out, int N) {
  constexpr int KT = 64;
  __shared__ float4 Wf4[KT / 4][64];  // Wf4[kb][c] = W[k0+4kb .. +3][c], 16 KB
  const int lane = threadIdx.x & 63;
  const int row0 = (blockIdx.x * 4 + (threadIdx.x >> 6)) * 8;
  float acc[8] = {0.f, 0.f, 0.f, 0.f, 0.f, 0.f, 0.f, 0.f};

  for (int k0 = 0; k0 < K; k0 += KT) {
    if (k0) __syncthreads();
    for (int i = threadIdx.x; i < (KT / 4) * 64; i += 256) {
      int kb = i >> 6, c = i & 63;
      const float* g = W + (size_t)(k0 + 4 * kb) * HID + c;
      Wf4[kb][c] = make_float4(g[0], g[HID], g[2 * HID], g[3 * HID]);
    }
    __syncthreads();
    if (row0 + 8 <= N) {
      const float* xp = x + (size_t)row0 * K + k0;
#pragma unroll 2
      for (int kb = 0; kb < KT / 4; ++kb) {
        float4 wf = Wf4[kb][lane];
#pragma unroll
        for (int r = 0; r < 8; ++r) {
          float4 xv = *(const float4*)(xp + (size_t)r * K + 4 * kb);
          acc[r] = fmaf(xv.w, wf.w, fmaf(xv.z, wf.z, fmaf(xv.y, wf.y, fmaf(xv.x, wf.x, acc[r]))));
        }
      }
    } else if (row0 < N) {
      const float* xp = x + (size_t)row0 * K + k0;
      int nr = N - row0;
      for (int kb = 0; kb < KT / 4; ++kb) {
        float4 wf = Wf4[kb][lane];
        for (int r = 0; r < nr; ++r) {
          float4 xv = *(const float4*)(xp + (size_t)r * K + 4 * kb);
          acc[r] = fmaf(xv.w, wf.w, fmaf(xv.z, wf.z, fmaf(xv.y, wf.y, fmaf(xv.x, wf.x, acc[r]))));
        }
      }
    }
  }
  if (row0 >= N) return;
  size_t o = (size_t)row0 * HID + lane;
  int nr = min(8, N - row0);
#pragma unroll
  for (int r = 0; r < 8; ++r)
    if (r < nr) out[o + (size_t)r * HID] = acc[r];
}

// ---------- fused aggregation ----------
// out[d] = sum_{e:dst=d} norm_e*h[src_e] + dinv[d]^2*h[d] + b  (+relu+L2norm)
// one wave per node, lane = feature; edge loop unrolled x4 for MLP.

template <bool RELU_NORM>
__global__ void agg_kernel(const int* __restrict__ rowptr, const int2* __restrict__ epack,
                           const float* __restrict__ dinv, const float* __restrict__ h,
                           const float* __restrict__ bias, float* __restrict__ out, int N) {
  int wv = (blockIdx.x * blockDim.x + threadIdx.x) >> 6;
  int lane = threadIdx.x & 63;
  if (wv >= N) return;
  int beg = rowptr[wv];
  int end = rowptr[wv + 1];
  float di = dinv[wv];
  float acc = di * di * h[(size_t)wv * HID + lane] + bias[lane];
  int j = beg;
  for (; j + 4 <= end; j += 4) {
    int2 e0 = epack[j], e1 = epack[j + 1], e2 = epack[j + 2], e3 = epack[j + 3];
    float h0 = h[(size_t)e0.x * HID + lane];
    float h1 = h[(size_t)e1.x * HID + lane];
    float h2 = h[(size_t)e2.x * HID + lane];
    float h3 = h[(size_t)e3.x * HID + lane];
    acc = fmaf(__int_as_float(e0.y), h0, acc);
    acc = fmaf(__int_as_float(e1.y), h1, acc);
    acc = fmaf(__int_as_float(e2.y), h2, acc);
    acc = fmaf(__int_as_float(e3.y), h3, acc);
  }
  for (; j < end; ++j) {
    int2 e0 = epack[j];
    acc = fmaf(__int_as_float(e0.y), h[(size_t)e0.x * HID + lane], acc);
  }
  size_t o = (size_t)wv * HID + lane;
  if (RELU_NORM) {
    float v = fmaxf(acc, 0.f);
    float ss = v * v;
#pragma unroll
    for (int off = 32; off; off >>= 1) ss += __shfl_xor(ss, off, 64);
    out[o] = v / fmaxf(sqrtf(ss), 1e-12f);
  } else {
    out[o] = acc;
  }
}

// ---------- atomic fallback path (only if ws too small for CSR) ----------

__global__ void init_agg_kernel(const float* __restrict__ dinv, const float* __restrict__ h,
                                const float* __restrict__ bias, float* __restrict__ out, int N) {
  int t = blockIdx.x * blockDim.x + threadIdx.x;
  int i = t >> 6, f = t & 63;
  if (i >= N) return;
  float di = dinv[i];
  out[t] = di * di * h[t] + bias[f];
}

__global__ void edge_atomic_kernel(const int* __restrict__ src, const int* __restrict__ dst,
                                   const float* __restrict__ dinv, const float* __restrict__ h,
                                   float* __restrict__ out, int E) {
  int t = blockIdx.x * blockDim.x + threadIdx.x;
  int e = t >> 6;
  if (e >= E) return;
  int f = t & 63;
  int s = src[e], d = dst[e];
  atomicAdd(&out[(size_t)d * HID + f], dinv[s] * dinv[d] * h[(size_t)s * HID + f]);
}

__global__ void relu_norm_kernel(float* __restrict__ hbuf, int N) {
  int t = blockIdx.x * blockDim.x + threadIdx.x;
  int i = t >> 6;
  if (i >= N) return;
  float v = fmaxf(hbuf[t], 0.f);
  float ss = v * v;
#pragma unroll
  for (int off = 32; off; off >>= 1) ss += __shfl_xor(ss, off, 64);
  hbuf[t] = v / fmaxf(sqrtf(ss), 1e-12f);
}

// ---------- host ----------

extern "C" void kernel_launch(void* const* d_in, const int* in_sizes, int n_in,
                              void* d_out, int out_size, void* d_ws, size_t ws_size,
                              hipStream_t stream) {
  const float* x  = (const float*)d_in[0];
  const int*   ei = (const int*)d_in[1];
  const float* W1 = (const float*)d_in[2];
  const float* b1 = (const float*)d_in[3];
  const float* W2 = (const float*)d_in[4];
  const float* b2 = (const float*)d_in[5];
  const float* W3 = (const float*)d_in[6];
  const float* b3 = (const float*)d_in[7];
  float* out = (float*)d_out;

  const int IN = in_sizes[2] / HID;   // 256
  const int N  = in_sizes[0] / IN;    // 100000
  const int E  = in_sizes[1] / 2;     // 1600000
  const int* srcI = ei;
  const int* dstI = ei + E;

  char* w = (char*)d_ws;
  size_t off = 0;
  auto alloc = [&](size_t bytes) { void* p = w + off; off = align256(off + bytes); return p; };
  float* A      = (float*)alloc((size_t)N * HID * 4);
  float* dinv   = (float*)alloc((size_t)N * 4);
  int*   cnt    = (int*)alloc((size_t)N * 4);
  size_t base_need = off;
  int*   rowptr = (int*)alloc((size_t)(N + 1) * 4);
  int*   cursor = (int*)alloc((size_t)N * 4);
  int2*  epack  = (int2*)alloc((size_t)E * 8);
  size_t csr_need = off;

  if (base_need > ws_size) return;
  const bool use_csr = (csr_need <= ws_size);

  const int blkE    = (E + 255) / 256;
  const int blkN    = (N + 255) / 256;
  const int blkRow  = (N + 31) / 32;          // gemm: 4 waves/block * 8 rows/wave
  const int blkWave = (N * 64 + 255) / 256;   // wave-per-node kernels
  const int blkEF   = ((size_t)E * 64 + 255) / 256;

  hipMemsetAsync(cnt, 0, (size_t)N * 4, stream);
  count_dst_kernel<<<blkE, 256, 0, stream>>>(dstI, cnt, E);
  dinv_kernel<<<blkN, 256, 0, stream>>>(cnt, dinv, N);

  if (use_csr) {
    scan_kernel<<<1, 1024, 0, stream>>>(cnt, rowptr, cursor, N);
    scatter_kernel<<<blkE, 256, 0, stream>>>(srcI, dstI, dinv, cursor, epack, E);

    gemm_kernel<256><<<blkRow, 256, 0, stream>>>(x, W1, A, N);
    agg_kernel<true><<<blkWave, 256, 0, stream>>>(rowptr, epack, dinv, A, b1, out, N);
    gemm_kernel<64><<<blkRow, 256, 0, stream>>>(out, W2, A, N);
    agg_kernel<true><<<blkWave, 256, 0, stream>>>(rowptr, epack, dinv, A, b2, out, N);
    gemm_kernel<64><<<blkRow, 256, 0, stream>>>(out, W3, A, N);
    agg_kernel<false><<<blkWave, 256, 0, stream>>>(rowptr, epack, dinv, A, b3, out, N);
  } else {
    gemm_kernel<256><<<blkRow, 256, 0, stream>>>(x, W1, A, N);
    init_agg_kernel<<<blkWave, 256, 0, stream>>>(dinv, A, b1, out, N);
    edge_atomic_kernel<<<blkEF, 256, 0, stream>>>(srcI, dstI, dinv, A, out, E);
    relu_norm_kernel<<<blkWave, 256, 0, stream>>>(out, N);

    gemm_kernel<64><<<blkRow, 256, 0, stream>>>(out, W2, A, N);
    init_agg_kernel<<<blkWave, 256, 0, stream>>>(dinv, A, b2, out, N);
    edge_atomic_kernel<<<blkEF, 256, 0, stream>>>(srcI, dstI, dinv, A, out, E);
    relu_norm_kernel<<<blkWave, 256, 0, stream>>>(out, N);

    gemm_kernel<64><<<blkRow, 256, 0, stream>>>(out, W3, A, N);
    init_agg_kernel<<<blkWave, 256, 0, stream>>>(dinv, A, b3, out, N);
    edge_atomic_kernel<<<blkEF, 256, 0, stream>>>(srcI, dstI, dinv, A, out, E);
  }
}

// Round 3
// 863.567 us; speedup vs baseline: 1.5462x; 1.2249x over previous
//
#include <hip/hip_runtime.h>
#include <math.h>

#define HID 64
#define KT 64

static inline size_t align256(size_t x) { return (x + 255) & ~(size_t)255; }

__device__ inline void gld_lds16(const float* g, float* lds) {
  __builtin_amdgcn_global_load_lds((const __attribute__((address_space(1))) void*)g,
                                   (__attribute__((address_space(3))) void*)lds, 16, 0, 0);
}

// ---------- graph preprocessing ----------

__global__ void count_dst_kernel(const int* __restrict__ dst, int* __restrict__ cnt, int E) {
  int e = blockIdx.x * blockDim.x + threadIdx.x;
  if (e < E) atomicAdd(&cnt[dst[e]], 1);
}

__global__ void dinv_kernel(const int* __restrict__ cnt, float* __restrict__ dinv, int N) {
  int i = blockIdx.x * blockDim.x + threadIdx.x;
  if (i < N) dinv[i] = rsqrtf((float)(cnt[i] + 1));  // +1 self-loop; deg >= 1 always
}

// single-block exclusive scan of cnt[0..N) -> rowptr[0..N], cursor copy
__global__ __launch_bounds__(1024) void scan_kernel(const int* __restrict__ cnt,
                                                    int* __restrict__ rowptr,
                                                    int* __restrict__ cursor, int N) {
  __shared__ int part[1024];
  int t = threadIdx.x;
  int chunk = (N + 1023) >> 10;
  int b = t * chunk;
  int e = min(b + chunk, N);
  int s = 0;
  for (int i = b; i < e; ++i) s += cnt[i];
  part[t] = s;
  __syncthreads();
  for (int off = 1; off < 1024; off <<= 1) {
    int v = (t >= off) ? part[t - off] : 0;
    __syncthreads();
    part[t] += v;
    __syncthreads();
  }
  int run = (t == 0) ? 0 : part[t - 1];
  for (int i = b; i < e; ++i) {
    rowptr[i] = run;
    cursor[i] = run;
    run += cnt[i];
  }
  if (t == 0) rowptr[N] = part[1023];
}

// pack (src, norm) into one int2 per edge, dst-sorted via cursor
__global__ void scatter_kernel(const int* __restrict__ src, const int* __restrict__ dst,
                               const float* __restrict__ dinv, int* __restrict__ cursor,
                               int2* __restrict__ epack, int E) {
  int e = blockIdx.x * blockDim.x + threadIdx.x;
  if (e >= E) return;
  int s = src[e], d = dst[e];
  int pos = atomicAdd(&cursor[d], 1);
  epack[pos] = make_int2(s, __float_as_int(dinv[s] * dinv[d]));
}

// ---------- GEMM: out[N,64] = x[N,K] @ W[K,64] (bias fused into agg) ----------
// Block = 64 rows. Per k0-tile: stage x[64][KT] (16 KB) + W[KT][64] (16 KB) into
// LDS via global_load_lds_dwordx4 (coalesced, 1 KB per wave-instruction).
// Compute: wave w -> rows w*16..w*16+15, lane = out col. x via LDS broadcast
// (free), W via stride-64 b32 (2-way alias = free).

template <int K>
__global__ __launch_bounds__(256, 4) void gemm_kernel(const float* __restrict__ x,
                                                      const float* __restrict__ W,
                                                      float* __restrict__ out, int N) {
  __shared__ float Xs[64 * KT];  // [row][kk]
  __shared__ float Ws[KT * 64];  // [kk][col]
  const int t = threadIdx.x;
  const int lane = t & 63;
  const int w = t >> 6;
  const int row0 = blockIdx.x * 64;
  float acc[16];
#pragma unroll
  for (int r = 0; r < 16; ++r) acc[r] = 0.f;

  for (int k0 = 0; k0 < K; k0 += KT) {
    if (k0) __syncthreads();
    const float* Wg = W + (size_t)k0 * HID;
#pragma unroll
    for (int c = 0; c < 4; ++c) {
      int idx = c * 256 + t;  // float4 index in 4096-float tile; lds = idx*16 B
      gld_lds16(Wg + idx * 4, &Ws[idx * 4]);
      int grow = min(row0 + (idx >> 4), N - 1);
      gld_lds16(x + (size_t)grow * K + k0 + ((idx & 15) << 2), &Xs[idx * 4]);
    }
    __syncthreads();  // drains vmcnt(0) -> staged data visible
    const float* Xw = &Xs[(w * 16) * KT];
#pragma unroll 2
    for (int kb = 0; kb < KT / 4; ++kb) {
      float w0 = Ws[(4 * kb + 0) * HID + lane];
      float w1 = Ws[(4 * kb + 1) * HID + lane];
      float w2 = Ws[(4 * kb + 2) * HID + lane];
      float w3 = Ws[(4 * kb + 3) * HID + lane];
#pragma unroll
      for (int r = 0; r < 16; ++r) {
        float4 xv = *(const float4*)(Xw + r * KT + 4 * kb);
        acc[r] = fmaf(xv.w, w3, fmaf(xv.z, w2, fmaf(xv.y, w1, fmaf(xv.x, w0, acc[r]))));
      }
    }
  }
  const int rbase = row0 + w * 16;
#pragma unroll
  for (int r = 0; r < 16; ++r) {
    int row = rbase + r;
    if (row < N) out[(size_t)row * HID + lane] = acc[r];
  }
}

// ---------- fused aggregation ----------
// out[d] = sum_{e:dst=d} norm_e*h[src_e] + dinv[d]^2*h[d] + b  (+relu+L2norm)
// one wave per node, lane = feature; 8 gathers in flight.

template <bool RELU_NORM>
__global__ void agg_kernel(const int* __restrict__ rowptr, const int2* __restrict__ epack,
                           const float* __restrict__ dinv, const float* __restrict__ h,
                           const float* __restrict__ bias, float* __restrict__ out, int N) {
  int wv = (blockIdx.x * blockDim.x + threadIdx.x) >> 6;
  int lane = threadIdx.x & 63;
  if (wv >= N) return;
  int beg = rowptr[wv];
  int end = rowptr[wv + 1];
  float di = dinv[wv];
  float acc = di * di * h[(size_t)wv * HID + lane] + bias[lane];
  int j = beg;
  for (; j + 8 <= end; j += 8) {
    int2 e[8];
    float hv[8];
#pragma unroll
    for (int u = 0; u < 8; ++u) e[u] = epack[j + u];
#pragma unroll
    for (int u = 0; u < 8; ++u) hv[u] = h[(size_t)e[u].x * HID + lane];
#pragma unroll
    for (int u = 0; u < 8; ++u) acc = fmaf(__int_as_float(e[u].y), hv[u], acc);
  }
  for (; j < end; ++j) {
    int2 e0 = epack[j];
    acc = fmaf(__int_as_float(e0.y), h[(size_t)e0.x * HID + lane], acc);
  }
  size_t o = (size_t)wv * HID + lane;
  if (RELU_NORM) {
    float v = fmaxf(acc, 0.f);
    float ss = v * v;
#pragma unroll
    for (int off = 32; off; off >>= 1) ss += __shfl_xor(ss, off, 64);
    out[o] = v / fmaxf(sqrtf(ss), 1e-12f);
  } else {
    out[o] = acc;
  }
}

// ---------- atomic fallback path (only if ws too small for CSR) ----------

__global__ void init_agg_kernel(const float* __restrict__ dinv, const float* __restrict__ h,
                                const float* __restrict__ bias, float* __restrict__ out, int N) {
  int t = blockIdx.x * blockDim.x + threadIdx.x;
  int i = t >> 6, f = t & 63;
  if (i >= N) return;
  float di = dinv[i];
  out[t] = di * di * h[t] + bias[f];
}

__global__ void edge_atomic_kernel(const int* __restrict__ src, const int* __restrict__ dst,
                                   const float* __restrict__ dinv, const float* __restrict__ h,
                                   float* __restrict__ out, int E) {
  int t = blockIdx.x * blockDim.x + threadIdx.x;
  int e = t >> 6;
  if (e >= E) return;
  int f = t & 63;
  int s = src[e], d = dst[e];
  atomicAdd(&out[(size_t)d * HID + f], dinv[s] * dinv[d] * h[(size_t)s * HID + f]);
}

__global__ void relu_norm_kernel(float* __restrict__ hbuf, int N) {
  int t = blockIdx.x * blockDim.x + threadIdx.x;
  int i = t >> 6;
  if (i >= N) return;
  float v = fmaxf(hbuf[t], 0.f);
  float ss = v * v;
#pragma unroll
  for (int off = 32; off; off >>= 1) ss += __shfl_xor(ss, off, 64);
  hbuf[t] = v / fmaxf(sqrtf(ss), 1e-12f);
}

// ---------- host ----------

extern "C" void kernel_launch(void* const* d_in, const int* in_sizes, int n_in,
                              void* d_out, int out_size, void* d_ws, size_t ws_size,
                              hipStream_t stream) {
  const float* x  = (const float*)d_in[0];
  const int*   ei = (const int*)d_in[1];
  const float* W1 = (const float*)d_in[2];
  const float* b1 = (const float*)d_in[3];
  const float* W2 = (const float*)d_in[4];
  const float* b2 = (const float*)d_in[5];
  const float* W3 = (const float*)d_in[6];
  const float* b3 = (const float*)d_in[7];
  float* out = (float*)d_out;

  const int IN = in_sizes[2] / HID;   // 256
  const int N  = in_sizes[0] / IN;    // 100000
  const int E  = in_sizes[1] / 2;     // 1600000
  const int* srcI = ei;
  const int* dstI = ei + E;

  char* w = (char*)d_ws;
  size_t off = 0;
  auto alloc = [&](size_t bytes) { void* p = w + off; off = align256(off + bytes); return p; };
  float* A      = (float*)alloc((size_t)N * HID * 4);
  float* dinv   = (float*)alloc((size_t)N * 4);
  int*   cnt    = (int*)alloc((size_t)N * 4);
  size_t base_need = off;
  int*   rowptr = (int*)alloc((size_t)(N + 1) * 4);
  int*   cursor = (int*)alloc((size_t)N * 4);
  int2*  epack  = (int2*)alloc((size_t)E * 8);
  size_t csr_need = off;

  if (base_need > ws_size) return;
  const bool use_csr = (csr_need <= ws_size);

  const int blkE    = (E + 255) / 256;
  const int blkN    = (N + 255) / 256;
  const int blkRow  = (N + 63) / 64;          // gemm: 64 rows/block
  const int blkWave = (N * 64 + 255) / 256;   // wave-per-node kernels
  const int blkEF   = ((size_t)E * 64 + 255) / 256;

  hipMemsetAsync(cnt, 0, (size_t)N * 4, stream);
  count_dst_kernel<<<blkE, 256, 0, stream>>>(dstI, cnt, E);
  dinv_kernel<<<blkN, 256, 0, stream>>>(cnt, dinv, N);

  if (use_csr) {
    scan_kernel<<<1, 1024, 0, stream>>>(cnt, rowptr, cursor, N);
    scatter_kernel<<<blkE, 256, 0, stream>>>(srcI, dstI, dinv, cursor, epack, E);

    gemm_kernel<256><<<blkRow, 256, 0, stream>>>(x, W1, A, N);
    agg_kernel<true><<<blkWave, 256, 0, stream>>>(rowptr, epack, dinv, A, b1, out, N);
    gemm_kernel<64><<<blkRow, 256, 0, stream>>>(out, W2, A, N);
    agg_kernel<true><<<blkWave, 256, 0, stream>>>(rowptr, epack, dinv, A, b2, out, N);
    gemm_kernel<64><<<blkRow, 256, 0, stream>>>(out, W3, A, N);
    agg_kernel<false><<<blkWave, 256, 0, stream>>>(rowptr, epack, dinv, A, b3, out, N);
  } else {
    gemm_kernel<256><<<blkRow, 256, 0, stream>>>(x, W1, A, N);
    init_agg_kernel<<<blkWave, 256, 0, stream>>>(dinv, A, b1, out, N);
    edge_atomic_kernel<<<blkEF, 256, 0, stream>>>(srcI, dstI, dinv, A, out, E);
    relu_norm_kernel<<<blkWave, 256, 0, stream>>>(out, N);

    gemm_kernel<64><<<blkRow, 256, 0, stream>>>(out, W2, A, N);
    init_agg_kernel<<<blkWave, 256, 0, stream>>>(dinv, A, b2, out, N);
    edge_atomic_kernel<<<blkEF, 256, 0, stream>>>(srcI, dstI, dinv, A, out, E);
    relu_norm_kernel<<<blkWave, 256, 0, stream>>>(out, N);

    gemm_kernel<64><<<blkRow, 256, 0, stream>>>(out, W3, A, N);
    init_agg_kernel<<<blkWave, 256, 0, stream>>>(dinv, A, b3, out, N);
    edge_atomic_kernel<<<blkEF, 256, 0, stream>>>(srcI, dstI, dinv, A, out, E);
  }
}

// Round 4
// 647.384 us; speedup vs baseline: 2.0626x; 1.3339x over previous
//
#include <hip/hip_runtime.h>
#include <math.h>

#define HID 64
#define KT 64

static inline size_t align256(size_t x) { return (x + 255) & ~(size_t)255; }

__device__ inline void gld_lds16(const float* g, float* lds) {
  __builtin_amdgcn_global_load_lds((const __attribute__((address_space(1))) void*)g,
                                   (__attribute__((address_space(3))) void*)lds, 16, 0, 0);
}

// ---------- graph preprocessing ----------

__global__ void count_dst_kernel(const int* __restrict__ dst, int* __restrict__ cnt, int E) {
  int e = blockIdx.x * blockDim.x + threadIdx.x;
  if (e < E) atomicAdd(&cnt[dst[e]], 1);
}

__global__ void dinv_kernel(const int* __restrict__ cnt, float* __restrict__ dinv, int N) {
  int i = blockIdx.x * blockDim.x + threadIdx.x;
  if (i < N) dinv[i] = rsqrtf((float)(cnt[i] + 1));  // +1 self-loop; deg >= 1 always
}

// ---------- 3-phase hierarchical exclusive scan (cnt -> rowptr, cursor) ----------

__global__ __launch_bounds__(1024) void scan_local_kernel(const int* __restrict__ cnt,
                                                          int* __restrict__ rowptr,
                                                          int* __restrict__ bsum, int N) {
  __shared__ int sh[1024];
  int t = threadIdx.x;
  int i = blockIdx.x * 1024 + t;
  int v = (i < N) ? cnt[i] : 0;
  sh[t] = v;
  __syncthreads();
  for (int off = 1; off < 1024; off <<= 1) {
    int u = (t >= off) ? sh[t - off] : 0;
    __syncthreads();
    sh[t] += u;
    __syncthreads();
  }
  if (i < N) rowptr[i] = sh[t] - v;  // local exclusive
  if (t == 1023) bsum[blockIdx.x] = sh[t];
}

__global__ __launch_bounds__(1024) void scan_bsum_kernel(const int* __restrict__ bsum,
                                                         int* __restrict__ boff,
                                                         int* __restrict__ rowptr_last, int B) {
  __shared__ int sh[1024];
  int t = threadIdx.x;
  int v = (t < B) ? bsum[t] : 0;
  sh[t] = v;
  __syncthreads();
  for (int off = 1; off < 1024; off <<= 1) {
    int u = (t >= off) ? sh[t - off] : 0;
    __syncthreads();
    sh[t] += u;
    __syncthreads();
  }
  if (t < B) boff[t] = sh[t] - v;
  if (t == 1023) *rowptr_last = sh[t];
}

__global__ void scan_add_kernel(const int* __restrict__ boff, int* __restrict__ rowptr,
                                int* __restrict__ cursor, int N) {
  int i = blockIdx.x * blockDim.x + threadIdx.x;
  if (i >= N) return;
  int r = rowptr[i] + boff[i >> 10];
  rowptr[i] = r;
  cursor[i] = r;
}

// pack (src, norm) into one int2 per edge, dst-sorted via cursor
__global__ void scatter_kernel(const int* __restrict__ src, const int* __restrict__ dst,
                               const float* __restrict__ dinv, int* __restrict__ cursor,
                               int2* __restrict__ epack, int E) {
  int e = blockIdx.x * blockDim.x + threadIdx.x;
  if (e >= E) return;
  int s = src[e], d = dst[e];
  int pos = atomicAdd(&cursor[d], 1);
  epack[pos] = make_int2(s, __float_as_int(dinv[s] * dinv[d]));
}

// ---------- GEMM: out[N,64] = x[N,K] @ W[K,64] (bias fused into agg) ----------
// Block = 64 rows. Per k0-tile: stage x[64][KT] (16 KB) + W[KT][64] (16 KB) into
// LDS via global_load_lds_dwordx4 (coalesced, 1 KB per wave-instruction).
// Compute: wave w -> rows w*16..w*16+15, lane = out col. x via LDS broadcast
// (free), W via stride-64 b32 (2-way alias = free).

template <int K>
__global__ __launch_bounds__(256, 4) void gemm_kernel(const float* __restrict__ x,
                                                      const float* __restrict__ W,
                                                      float* __restrict__ out, int N) {
  __shared__ float Xs[64 * KT];  // [row][kk]
  __shared__ float Ws[KT * 64];  // [kk][col]
  const int t = threadIdx.x;
  const int lane = t & 63;
  const int w = t >> 6;
  const int row0 = blockIdx.x * 64;
  float acc[16];
#pragma unroll
  for (int r = 0; r < 16; ++r) acc[r] = 0.f;

  for (int k0 = 0; k0 < K; k0 += KT) {
    if (k0) __syncthreads();
    const float* Wg = W + (size_t)k0 * HID;
#pragma unroll
    for (int c = 0; c < 4; ++c) {
      int idx = c * 256 + t;  // float4 index in 4096-float tile; lds = idx*16 B
      gld_lds16(Wg + idx * 4, &Ws[idx * 4]);
      int grow = min(row0 + (idx >> 4), N - 1);
      gld_lds16(x + (size_t)grow * K + k0 + ((idx & 15) << 2), &Xs[idx * 4]);
    }
    __syncthreads();  // drains vmcnt(0) -> staged data visible
    const float* Xw = &Xs[(w * 16) * KT];
#pragma unroll 2
    for (int kb = 0; kb < KT / 4; ++kb) {
      float w0 = Ws[(4 * kb + 0) * HID + lane];
      float w1 = Ws[(4 * kb + 1) * HID + lane];
      float w2 = Ws[(4 * kb + 2) * HID + lane];
      float w3 = Ws[(4 * kb + 3) * HID + lane];
#pragma unroll
      for (int r = 0; r < 16; ++r) {
        float4 xv = *(const float4*)(Xw + r * KT + 4 * kb);
        acc[r] = fmaf(xv.w, w3, fmaf(xv.z, w2, fmaf(xv.y, w1, fmaf(xv.x, w0, acc[r]))));
      }
    }
  }
  const int rbase = row0 + w * 16;
#pragma unroll
  for (int r = 0; r < 16; ++r) {
    int row = rbase + r;
    if (row < N) out[(size_t)row * HID + lane] = acc[r];
  }
}

// ---------- fused aggregation ----------
// out[d] = sum_{e:dst=d} norm_e*h[src_e] + dinv[d]^2*h[d] + b  (+relu+L2norm)
// one wave per node, lane = feature; 8 gathers in flight.

template <bool RELU_NORM>
__global__ void agg_kernel(const int* __restrict__ rowptr, const int2* __restrict__ epack,
                           const float* __restrict__ dinv, const float* __restrict__ h,
                           const float* __restrict__ bias, float* __restrict__ out, int N) {
  int wv = (blockIdx.x * blockDim.x + threadIdx.x) >> 6;
  int lane = threadIdx.x & 63;
  if (wv >= N) return;
  int beg = rowptr[wv];
  int end = rowptr[wv + 1];
  float di = dinv[wv];
  float acc = di * di * h[(size_t)wv * HID + lane] + bias[lane];
  int j = beg;
  for (; j + 8 <= end; j += 8) {
    int2 e[8];
    float hv[8];
#pragma unroll
    for (int u = 0; u < 8; ++u) e[u] = epack[j + u];
#pragma unroll
    for (int u = 0; u < 8; ++u) hv[u] = h[(size_t)e[u].x * HID + lane];
#pragma unroll
    for (int u = 0; u < 8; ++u) acc = fmaf(__int_as_float(e[u].y), hv[u], acc);
  }
  for (; j < end; ++j) {
    int2 e0 = epack[j];
    acc = fmaf(__int_as_float(e0.y), h[(size_t)e0.x * HID + lane], acc);
  }
  size_t o = (size_t)wv * HID + lane;
  if (RELU_NORM) {
    float v = fmaxf(acc, 0.f);
    float ss = v * v;
#pragma unroll
    for (int off = 32; off; off >>= 1) ss += __shfl_xor(ss, off, 64);
    out[o] = v / fmaxf(sqrtf(ss), 1e-12f);
  } else {
    out[o] = acc;
  }
}

// ---------- atomic fallback path (only if ws too small for CSR) ----------

__global__ void init_agg_kernel(const float* __restrict__ dinv, const float* __restrict__ h,
                                const float* __restrict__ bias, float* __restrict__ out, int N) {
  int t = blockIdx.x * blockDim.x + threadIdx.x;
  int i = t >> 6, f = t & 63;
  if (i >= N) return;
  float di = dinv[i];
  out[t] = di * di * h[t] + bias[f];
}

__global__ void edge_atomic_kernel(const int* __restrict__ src, const int* __restrict__ dst,
                                   const float* __restrict__ dinv, const float* __restrict__ h,
                                   float* __restrict__ out, int E) {
  int t = blockIdx.x * blockDim.x + threadIdx.x;
  int e = t >> 6;
  if (e >= E) return;
  int f = t & 63;
  int s = src[e], d = dst[e];
  atomicAdd(&out[(size_t)d * HID + f], dinv[s] * dinv[d] * h[(size_t)s * HID + f]);
}

__global__ void relu_norm_kernel(float* __restrict__ hbuf, int N) {
  int t = blockIdx.x * blockDim.x + threadIdx.x;
  int i = t >> 6;
  if (i >= N) return;
  float v = fmaxf(hbuf[t], 0.f);
  float ss = v * v;
#pragma unroll
  for (int off = 32; off; off >>= 1) ss += __shfl_xor(ss, off, 64);
  hbuf[t] = v / fmaxf(sqrtf(ss), 1e-12f);
}

// ---------- host ----------

extern "C" void kernel_launch(void* const* d_in, const int* in_sizes, int n_in,
                              void* d_out, int out_size, void* d_ws, size_t ws_size,
                              hipStream_t stream) {
  const float* x  = (const float*)d_in[0];
  const int*   ei = (const int*)d_in[1];
  const float* W1 = (const float*)d_in[2];
  const float* b1 = (const float*)d_in[3];
  const float* W2 = (const float*)d_in[4];
  const float* b2 = (const float*)d_in[5];
  const float* W3 = (const float*)d_in[6];
  const float* b3 = (const float*)d_in[7];
  float* out = (float*)d_out;

  const int IN = in_sizes[2] / HID;   // 256
  const int N  = in_sizes[0] / IN;    // 100000
  const int E  = in_sizes[1] / 2;     // 1600000
  const int* srcI = ei;
  const int* dstI = ei + E;

  char* w = (char*)d_ws;
  size_t off = 0;
  auto alloc = [&](size_t bytes) { void* p = w + off; off = align256(off + bytes); return p; };
  float* A      = (float*)alloc((size_t)N * HID * 4);
  float* dinv   = (float*)alloc((size_t)N * 4);
  int*   cnt    = (int*)alloc((size_t)N * 4);
  size_t base_need = off;
  int*   rowptr = (int*)alloc((size_t)(N + 1) * 4);
  int*   cursor = (int*)alloc((size_t)N * 4);
  int*   bsum   = (int*)alloc(1024 * 4);
  int*   boff   = (int*)alloc(1024 * 4);
  int2*  epack  = (int2*)alloc((size_t)E * 8);
  size_t csr_need = off;

  if (base_need > ws_size) return;
  const bool use_csr = (csr_need <= ws_size);

  const int blkE    = (E + 255) / 256;
  const int blkN    = (N + 255) / 256;
  const int blkScan = (N + 1023) / 1024;      // 98
  const int blkRow  = (N + 63) / 64;          // gemm: 64 rows/block
  const int blkWave = (N * 64 + 255) / 256;   // wave-per-node kernels
  const int blkEF   = ((size_t)E * 64 + 255) / 256;

  hipMemsetAsync(cnt, 0, (size_t)N * 4, stream);
  count_dst_kernel<<<blkE, 256, 0, stream>>>(dstI, cnt, E);
  dinv_kernel<<<blkN, 256, 0, stream>>>(cnt, dinv, N);

  if (use_csr) {
    scan_local_kernel<<<blkScan, 1024, 0, stream>>>(cnt, rowptr, bsum, N);
    scan_bsum_kernel<<<1, 1024, 0, stream>>>(bsum, boff, rowptr + N, blkScan);
    scan_add_kernel<<<blkN, 256, 0, stream>>>(boff, rowptr, cursor, N);
    scatter_kernel<<<blkE, 256, 0, stream>>>(srcI, dstI, dinv, cursor, epack, E);

    gemm_kernel<256><<<blkRow, 256, 0, stream>>>(x, W1, A, N);
    agg_kernel<true><<<blkWave, 256, 0, stream>>>(rowptr, epack, dinv, A, b1, out, N);
    gemm_kernel<64><<<blkRow, 256, 0, stream>>>(out, W2, A, N);
    agg_kernel<true><<<blkWave, 256, 0, stream>>>(rowptr, epack, dinv, A, b2, out, N);
    gemm_kernel<64><<<blkRow, 256, 0, stream>>>(out, W3, A, N);
    agg_kernel<false><<<blkWave, 256, 0, stream>>>(rowptr, epack, dinv, A, b3, out, N);
  } else {
    gemm_kernel<256><<<blkRow, 256, 0, stream>>>(x, W1, A, N);
    init_agg_kernel<<<blkWave, 256, 0, stream>>>(dinv, A, b1, out, N);
    edge_atomic_kernel<<<blkEF, 256, 0, stream>>>(srcI, dstI, dinv, A, out, E);
    relu_norm_kernel<<<blkWave, 256, 0, stream>>>(out, N);

    gemm_kernel<64><<<blkRow, 256, 0, stream>>>(out, W2, A, N);
    init_agg_kernel<<<blkWave, 256, 0, stream>>>(dinv, A, b2, out, N);
    edge_atomic_kernel<<<blkEF, 256, 0, stream>>>(srcI, dstI, dinv, A, out, E);
    relu_norm_kernel<<<blkWave, 256, 0, stream>>>(out, N);

    gemm_kernel<64><<<blkRow, 256, 0, stream>>>(out, W3, A, N);
    init_agg_kernel<<<blkWave, 256, 0, stream>>>(dinv, A, b3, out, N);
    edge_atomic_kernel<<<blkEF, 256, 0, stream>>>(srcI, dstI, dinv, A, out, E);
  }
}

// Round 5
// 634.752 us; speedup vs baseline: 2.1036x; 1.0199x over previous
//
#include <hip/hip_runtime.h>
#include <hip/hip_bf16.h>
#include <math.h>

#define HID 64
#define KT 64

static inline size_t align256(size_t x) { return (x + 255) & ~(size_t)255; }

__device__ inline void gld_lds16(const float* g, float* lds) {
  __builtin_amdgcn_global_load_lds((const __attribute__((address_space(1))) void*)g,
                                   (__attribute__((address_space(3))) void*)lds, 16, 0, 0);
}

// ---------- graph preprocessing ----------

__global__ void count_dst_kernel(const int* __restrict__ dst, int* __restrict__ cnt, int E) {
  int e = blockIdx.x * blockDim.x + threadIdx.x;
  if (e < E) atomicAdd(&cnt[dst[e]], 1);
}

__global__ void dinv_kernel(const int* __restrict__ cnt, float* __restrict__ dinv, int N) {
  int i = blockIdx.x * blockDim.x + threadIdx.x;
  if (i < N) dinv[i] = rsqrtf((float)(cnt[i] + 1));  // +1 self-loop; deg >= 1 always
}

// ---------- 3-phase hierarchical exclusive scan (cnt -> rowptr, cursor) ----------

__global__ __launch_bounds__(1024) void scan_local_kernel(const int* __restrict__ cnt,
                                                          int* __restrict__ rowptr,
                                                          int* __restrict__ bsum, int N) {
  __shared__ int sh[1024];
  int t = threadIdx.x;
  int i = blockIdx.x * 1024 + t;
  int v = (i < N) ? cnt[i] : 0;
  sh[t] = v;
  __syncthreads();
  for (int off = 1; off < 1024; off <<= 1) {
    int u = (t >= off) ? sh[t - off] : 0;
    __syncthreads();
    sh[t] += u;
    __syncthreads();
  }
  if (i < N) rowptr[i] = sh[t] - v;  // local exclusive
  if (t == 1023) bsum[blockIdx.x] = sh[t];
}

__global__ __launch_bounds__(1024) void scan_bsum_kernel(const int* __restrict__ bsum,
                                                         int* __restrict__ boff,
                                                         int* __restrict__ rowptr_last, int B) {
  __shared__ int sh[1024];
  int t = threadIdx.x;
  int v = (t < B) ? bsum[t] : 0;
  sh[t] = v;
  __syncthreads();
  for (int off = 1; off < 1024; off <<= 1) {
    int u = (t >= off) ? sh[t - off] : 0;
    __syncthreads();
    sh[t] += u;
    __syncthreads();
  }
  if (t < B) boff[t] = sh[t] - v;
  if (t == 1023) *rowptr_last = sh[t];
}

__global__ void scan_add_kernel(const int* __restrict__ boff, int* __restrict__ rowptr,
                                int* __restrict__ cursor, int N) {
  int i = blockIdx.x * blockDim.x + threadIdx.x;
  if (i >= N) return;
  int r = rowptr[i] + boff[i >> 10];
  rowptr[i] = r;
  cursor[i] = r;
}

// pack (src, norm) into one int2 per edge, dst-sorted via cursor
__global__ void scatter_kernel(const int* __restrict__ src, const int* __restrict__ dst,
                               const float* __restrict__ dinv, int* __restrict__ cursor,
                               int2* __restrict__ epack, int E) {
  int e = blockIdx.x * blockDim.x + threadIdx.x;
  if (e >= E) return;
  int s = src[e], d = dst[e];
  int pos = atomicAdd(&cursor[d], 1);
  epack[pos] = make_int2(s, __float_as_int(dinv[s] * dinv[d]));
}

// ---------- GEMM: out[N,64] = x[N,K] @ W[K,64] (bias fused into agg) ----------
// Block = 64 rows; x/W tiles staged via global_load_lds_dwordx4; wave = 16 rows,
// lane = out col. OT selects fp32 or bf16 output (bf16 feeds the gather).

template <int K, typename OT>
__global__ __launch_bounds__(256, 4) void gemm_kernel(const float* __restrict__ x,
                                                      const float* __restrict__ W,
                                                      OT* __restrict__ out, int N) {
  __shared__ float Xs[64 * KT];  // [row][kk]
  __shared__ float Ws[KT * 64];  // [kk][col]
  const int t = threadIdx.x;
  const int lane = t & 63;
  const int w = t >> 6;
  const int row0 = blockIdx.x * 64;
  float acc[16];
#pragma unroll
  for (int r = 0; r < 16; ++r) acc[r] = 0.f;

  for (int k0 = 0; k0 < K; k0 += KT) {
    if (k0) __syncthreads();
    const float* Wg = W + (size_t)k0 * HID;
#pragma unroll
    for (int c = 0; c < 4; ++c) {
      int idx = c * 256 + t;  // float4 index in 4096-float tile
      gld_lds16(Wg + idx * 4, &Ws[idx * 4]);
      int grow = min(row0 + (idx >> 4), N - 1);
      gld_lds16(x + (size_t)grow * K + k0 + ((idx & 15) << 2), &Xs[idx * 4]);
    }
    __syncthreads();
    const float* Xw = &Xs[(w * 16) * KT];
#pragma unroll 2
    for (int kb = 0; kb < KT / 4; ++kb) {
      float w0 = Ws[(4 * kb + 0) * HID + lane];
      float w1 = Ws[(4 * kb + 1) * HID + lane];
      float w2 = Ws[(4 * kb + 2) * HID + lane];
      float w3 = Ws[(4 * kb + 3) * HID + lane];
#pragma unroll
      for (int r = 0; r < 16; ++r) {
        float4 xv = *(const float4*)(Xw + r * KT + 4 * kb);
        acc[r] = fmaf(xv.w, w3, fmaf(xv.z, w2, fmaf(xv.y, w1, fmaf(xv.x, w0, acc[r]))));
      }
    }
  }
  const int rbase = row0 + w * 16;
#pragma unroll
  for (int r = 0; r < 16; ++r) {
    int row = rbase + r;
    if (row < N) out[(size_t)row * HID + lane] = (OT)acc[r];
  }
}

// ---------- fused aggregation (bf16 gather buffer) ----------
// out[d] = sum_{e:dst=d} norm_e*h[src_e] + dinv[d]^2*h[d] + b  (+relu+L2norm)
// one wave per node, lane = feature; 8 gathers (128 B rows) in flight.

template <bool RELU_NORM>
__global__ void agg_kernel(const int* __restrict__ rowptr, const int2* __restrict__ epack,
                           const float* __restrict__ dinv, const __hip_bfloat16* __restrict__ h,
                           const float* __restrict__ bias, float* __restrict__ out, int N) {
  int wv = (blockIdx.x * blockDim.x + threadIdx.x) >> 6;
  int lane = threadIdx.x & 63;
  if (wv >= N) return;
  int beg = rowptr[wv];
  int end = rowptr[wv + 1];
  float di = dinv[wv];
  float acc = di * di * __bfloat162float(h[(size_t)wv * HID + lane]) + bias[lane];
  int j = beg;
  for (; j + 8 <= end; j += 8) {
    int2 e[8];
    float hv[8];
#pragma unroll
    for (int u = 0; u < 8; ++u) e[u] = epack[j + u];
#pragma unroll
    for (int u = 0; u < 8; ++u) hv[u] = __bfloat162float(h[(size_t)e[u].x * HID + lane]);
#pragma unroll
    for (int u = 0; u < 8; ++u) acc = fmaf(__int_as_float(e[u].y), hv[u], acc);
  }
  for (; j < end; ++j) {
    int2 e0 = epack[j];
    acc = fmaf(__int_as_float(e0.y), __bfloat162float(h[(size_t)e0.x * HID + lane]), acc);
  }
  size_t o = (size_t)wv * HID + lane;
  if (RELU_NORM) {
    float v = fmaxf(acc, 0.f);
    float ss = v * v;
#pragma unroll
    for (int off = 32; off; off >>= 1) ss += __shfl_xor(ss, off, 64);
    out[o] = v / fmaxf(sqrtf(ss), 1e-12f);
  } else {
    out[o] = acc;
  }
}

// ---------- atomic fallback path (fp32; only if ws too small for CSR) ----------

__global__ void init_agg_kernel(const float* __restrict__ dinv, const float* __restrict__ h,
                                const float* __restrict__ bias, float* __restrict__ out, int N) {
  int t = blockIdx.x * blockDim.x + threadIdx.x;
  int i = t >> 6, f = t & 63;
  if (i >= N) return;
  float di = dinv[i];
  out[t] = di * di * h[t] + bias[f];
}

__global__ void edge_atomic_kernel(const int* __restrict__ src, const int* __restrict__ dst,
                                   const float* __restrict__ dinv, const float* __restrict__ h,
                                   float* __restrict__ out, int E) {
  int t = blockIdx.x * blockDim.x + threadIdx.x;
  int e = t >> 6;
  if (e >= E) return;
  int f = t & 63;
  int s = src[e], d = dst[e];
  atomicAdd(&out[(size_t)d * HID + f], dinv[s] * dinv[d] * h[(size_t)s * HID + f]);
}

__global__ void relu_norm_kernel(float* __restrict__ hbuf, int N) {
  int t = blockIdx.x * blockDim.x + threadIdx.x;
  int i = t >> 6;
  if (i >= N) return;
  float v = fmaxf(hbuf[t], 0.f);
  float ss = v * v;
#pragma unroll
  for (int off = 32; off; off >>= 1) ss += __shfl_xor(ss, off, 64);
  hbuf[t] = v / fmaxf(sqrtf(ss), 1e-12f);
}

// ---------- host ----------

extern "C" void kernel_launch(void* const* d_in, const int* in_sizes, int n_in,
                              void* d_out, int out_size, void* d_ws, size_t ws_size,
                              hipStream_t stream) {
  const float* x  = (const float*)d_in[0];
  const int*   ei = (const int*)d_in[1];
  const float* W1 = (const float*)d_in[2];
  const float* b1 = (const float*)d_in[3];
  const float* W2 = (const float*)d_in[4];
  const float* b2 = (const float*)d_in[5];
  const float* W3 = (const float*)d_in[6];
  const float* b3 = (const float*)d_in[7];
  float* out = (float*)d_out;

  const int IN = in_sizes[2] / HID;   // 256
  const int N  = in_sizes[0] / IN;    // 100000
  const int E  = in_sizes[1] / 2;     // 1600000
  const int* srcI = ei;
  const int* dstI = ei + E;

  char* w = (char*)d_ws;
  size_t off = 0;
  auto alloc = [&](size_t bytes) { void* p = w + off; off = align256(off + bytes); return p; };
  float* A      = (float*)alloc((size_t)N * HID * 4);  // fp32 fallback / bf16 gather buffer
  float* dinv   = (float*)alloc((size_t)N * 4);
  int*   cnt    = (int*)alloc((size_t)N * 4);
  size_t base_need = off;
  int*   rowptr = (int*)alloc((size_t)(N + 1) * 4);
  int*   cursor = (int*)alloc((size_t)N * 4);
  int*   bsum   = (int*)alloc(1024 * 4);
  int*   boff   = (int*)alloc(1024 * 4);
  int2*  epack  = (int2*)alloc((size_t)E * 8);
  size_t csr_need = off;

  if (base_need > ws_size) return;
  const bool use_csr = (csr_need <= ws_size);
  __hip_bfloat16* Ab = (__hip_bfloat16*)A;

  const int blkE    = (E + 255) / 256;
  const int blkN    = (N + 255) / 256;
  const int blkScan = (N + 1023) / 1024;
  const int blkRow  = (N + 63) / 64;
  const int blkWave = (N * 64 + 255) / 256;
  const int blkEF   = ((size_t)E * 64 + 255) / 256;

  hipMemsetAsync(cnt, 0, (size_t)N * 4, stream);
  count_dst_kernel<<<blkE, 256, 0, stream>>>(dstI, cnt, E);
  dinv_kernel<<<blkN, 256, 0, stream>>>(cnt, dinv, N);

  if (use_csr) {
    scan_local_kernel<<<blkScan, 1024, 0, stream>>>(cnt, rowptr, bsum, N);
    scan_bsum_kernel<<<1, 1024, 0, stream>>>(bsum, boff, rowptr + N, blkScan);
    scan_add_kernel<<<blkN, 256, 0, stream>>>(boff, rowptr, cursor, N);
    scatter_kernel<<<blkE, 256, 0, stream>>>(srcI, dstI, dinv, cursor, epack, E);

    gemm_kernel<256><<<blkRow, 256, 0, stream>>>(x, W1, Ab, N);
    agg_kernel<true><<<blkWave, 256, 0, stream>>>(rowptr, epack, dinv, Ab, b1, out, N);
    gemm_kernel<64><<<blkRow, 256, 0, stream>>>(out, W2, Ab, N);
    agg_kernel<true><<<blkWave, 256, 0, stream>>>(rowptr, epack, dinv, Ab, b2, out, N);
    gemm_kernel<64><<<blkRow, 256, 0, stream>>>(out, W3, Ab, N);
    agg_kernel<false><<<blkWave, 256, 0, stream>>>(rowptr, epack, dinv, Ab, b3, out, N);
  } else {
    gemm_kernel<256><<<blkRow, 256, 0, stream>>>(x, W1, A, N);
    init_agg_kernel<<<blkWave, 256, 0, stream>>>(dinv, A, b1, out, N);
    edge_atomic_kernel<<<blkEF, 256, 0, stream>>>(srcI, dstI, dinv, A, out, E);
    relu_norm_kernel<<<blkWave, 256, 0, stream>>>(out, N);

    gemm_kernel<64><<<blkRow, 256, 0, stream>>>(out, W2, A, N);
    init_agg_kernel<<<blkWave, 256, 0, stream>>>(dinv, A, b2, out, N);
    edge_atomic_kernel<<<blkEF, 256, 0, stream>>>(srcI, dstI, dinv, A, out, E);
    relu_norm_kernel<<<blkWave, 256, 0, stream>>>(out, N);

    gemm_kernel<64><<<blkRow, 256, 0, stream>>>(out, W3, A, N);
    init_agg_kernel<<<blkWave, 256, 0, stream>>>(dinv, A, b3, out, N);
    edge_atomic_kernel<<<blkEF, 256, 0, stream>>>(srcI, dstI, dinv, A, out, E);
  }
}

// Round 6
// 522.739 us; speedup vs baseline: 2.5544x; 1.2143x over previous
//
#include <hip/hip_runtime.h>
#include <hip/hip_bf16.h>
#include <math.h>

#define HID 64
#define KT 64

static inline size_t align256(size_t x) { return (x + 255) & ~(size_t)255; }

__device__ inline void gld_lds16(const float* g, float* lds) {
  __builtin_amdgcn_global_load_lds((const __attribute__((address_space(1))) void*)g,
                                   (__attribute__((address_space(3))) void*)lds, 16, 0, 0);
}

// ---------- graph preprocessing ----------

__global__ void count_dst_kernel(const int* __restrict__ dst, int* __restrict__ cnt, int E) {
  int e = blockIdx.x * blockDim.x + threadIdx.x;
  if (e < E) atomicAdd(&cnt[dst[e]], 1);
}

__global__ void dinv_kernel(const int* __restrict__ cnt, float* __restrict__ dinv, int N) {
  int i = blockIdx.x * blockDim.x + threadIdx.x;
  if (i < N) dinv[i] = rsqrtf((float)(cnt[i] + 1));  // +1 self-loop; deg >= 1 always
}

// ---------- 3-phase hierarchical exclusive scan (cnt -> rowptr, cursor) ----------

__global__ __launch_bounds__(1024) void scan_local_kernel(const int* __restrict__ cnt,
                                                          int* __restrict__ rowptr,
                                                          int* __restrict__ bsum, int N) {
  __shared__ int sh[1024];
  int t = threadIdx.x;
  int i = blockIdx.x * 1024 + t;
  int v = (i < N) ? cnt[i] : 0;
  sh[t] = v;
  __syncthreads();
  for (int off = 1; off < 1024; off <<= 1) {
    int u = (t >= off) ? sh[t - off] : 0;
    __syncthreads();
    sh[t] += u;
    __syncthreads();
  }
  if (i < N) rowptr[i] = sh[t] - v;  // local exclusive
  if (t == 1023) bsum[blockIdx.x] = sh[t];
}

__global__ __launch_bounds__(1024) void scan_bsum_kernel(const int* __restrict__ bsum,
                                                         int* __restrict__ boff,
                                                         int* __restrict__ rowptr_last, int B) {
  __shared__ int sh[1024];
  int t = threadIdx.x;
  int v = (t < B) ? bsum[t] : 0;
  sh[t] = v;
  __syncthreads();
  for (int off = 1; off < 1024; off <<= 1) {
    int u = (t >= off) ? sh[t - off] : 0;
    __syncthreads();
    sh[t] += u;
    __syncthreads();
  }
  if (t < B) boff[t] = sh[t] - v;
  if (t == 1023) *rowptr_last = sh[t];
}

__global__ void scan_add_kernel(const int* __restrict__ boff, int* __restrict__ rowptr,
                                int* __restrict__ cursor, int N) {
  int i = blockIdx.x * blockDim.x + threadIdx.x;
  if (i >= N) return;
  int r = rowptr[i] + boff[i >> 10];
  rowptr[i] = r;
  cursor[i] = r;
}

// pack (src, norm) into one int2 per edge, dst-sorted via cursor
__global__ void scatter_kernel(const int* __restrict__ src, const int* __restrict__ dst,
                               const float* __restrict__ dinv, int* __restrict__ cursor,
                               int2* __restrict__ epack, int E) {
  int e = blockIdx.x * blockDim.x + threadIdx.x;
  if (e >= E) return;
  int s = src[e], d = dst[e];
  int pos = atomicAdd(&cursor[d], 1);
  epack[pos] = make_int2(s, __float_as_int(dinv[s] * dinv[d]));
}

// ---------- GEMM: out[N,64] = x[N,K] @ W[K,64] (bias fused into agg) ----------
// Block = 64 rows; x/W staged via global_load_lds_dwordx4. 4x4 micro-tile:
// lane = (rg=lane>>4 -> rows w*16+rg*4+{0..3}, cg=lane&15 -> cols cg*4+{0..3}).
// Xs k-groups XOR-swizzled by (row>>2)&3 on the GLOBAL side of the staging DMA
// (LDS side must stay lane-contiguous) -> conflict-free x reads.

template <int K, typename OT>
__global__ __launch_bounds__(256, 4) void gemm_kernel(const float* __restrict__ x,
                                                      const float* __restrict__ W,
                                                      OT* __restrict__ out, int N) {
  __shared__ float Xs[64 * KT];  // [row][swizzled k-group]
  __shared__ float Ws[KT * 64];  // [kk][col]
  const int t = threadIdx.x;
  const int lane = t & 63;
  const int w = t >> 6;
  const int rg = lane >> 4;
  const int cg = lane & 15;
  const int row0 = blockIdx.x * 64;
  float4 acc[4];
#pragma unroll
  for (int r = 0; r < 4; ++r) acc[r] = make_float4(0.f, 0.f, 0.f, 0.f);

  for (int k0 = 0; k0 < K; k0 += KT) {
    if (k0) __syncthreads();
    const float* Wg = W + (size_t)k0 * HID;
#pragma unroll
    for (int c = 0; c < 4; ++c) {
      int idx = c * 256 + t;  // float4 slot in 4096-float tile
      gld_lds16(Wg + idx * 4, &Ws[idx * 4]);
      int srow = idx >> 4;                         // LDS row for this slot
      int sg = (idx & 15) ^ ((srow >> 2) & 3);     // swizzled source k-group
      int grow = min(row0 + srow, N - 1);
      gld_lds16(x + (size_t)grow * K + k0 + (sg << 2), &Xs[idx * 4]);
    }
    __syncthreads();
    const int rbase = w * 16 + rg * 4;
#pragma unroll 4
    for (int kb = 0; kb < KT / 4; ++kb) {
      float4 wq0 = *(const float4*)&Ws[(4 * kb + 0) * HID + cg * 4];
      float4 wq1 = *(const float4*)&Ws[(4 * kb + 1) * HID + cg * 4];
      float4 wq2 = *(const float4*)&Ws[(4 * kb + 2) * HID + cg * 4];
      float4 wq3 = *(const float4*)&Ws[(4 * kb + 3) * HID + cg * 4];
      const int sg = (kb ^ rg) << 2;  // (row>>2)&3 == rg for rows rbase..rbase+3
#pragma unroll
      for (int r = 0; r < 4; ++r) {
        float4 xv = *(const float4*)&Xs[(rbase + r) * KT + sg];
        acc[r].x = fmaf(xv.w, wq3.x, fmaf(xv.z, wq2.x, fmaf(xv.y, wq1.x, fmaf(xv.x, wq0.x, acc[r].x))));
        acc[r].y = fmaf(xv.w, wq3.y, fmaf(xv.z, wq2.y, fmaf(xv.y, wq1.y, fmaf(xv.x, wq0.y, acc[r].y))));
        acc[r].z = fmaf(xv.w, wq3.z, fmaf(xv.z, wq2.z, fmaf(xv.y, wq1.z, fmaf(xv.x, wq0.z, acc[r].z))));
        acc[r].w = fmaf(xv.w, wq3.w, fmaf(xv.z, wq2.w, fmaf(xv.y, wq1.w, fmaf(xv.x, wq0.w, acc[r].w))));
      }
    }
  }
#pragma unroll
  for (int r = 0; r < 4; ++r) {
    int row = row0 + w * 16 + rg * 4 + r;
    if (row < N) {
      OT* o = out + (size_t)row * HID + cg * 4;
      o[0] = (OT)acc[r].x; o[1] = (OT)acc[r].y; o[2] = (OT)acc[r].z; o[3] = (OT)acc[r].w;
    }
  }
}

// ---------- fused aggregation (bf16 gather, 2 features/lane, 2 nodes/wave) ----------
// out[d] = sum_{e:dst=d} norm_e*h[src_e] + dinv[d]^2*h[d] + b  (+relu+L2norm)

__device__ inline float bf_lo(unsigned int u) { return __uint_as_float(u << 16); }
__device__ inline float bf_hi(unsigned int u) { return __uint_as_float(u & 0xffff0000u); }

template <bool RELU_NORM>
__global__ void agg_kernel(const int* __restrict__ rowptr, const int2* __restrict__ epack,
                           const float* __restrict__ dinv, const unsigned int* __restrict__ h32,
                           const float* __restrict__ bias, float* __restrict__ out, int N) {
  int pair = (blockIdx.x * blockDim.x + threadIdx.x) >> 6;
  int lane = threadIdx.x & 63;
  int node = pair * 2 + (lane >> 5);
  if (node >= N) return;
  int sub = lane & 31;  // features sub*2, sub*2+1
  int beg = rowptr[node];
  int end = rowptr[node + 1];
  float di = dinv[node];
  unsigned int su = h32[(size_t)node * 32 + sub];
  float acc0 = di * di * bf_lo(su) + bias[sub * 2];
  float acc1 = di * di * bf_hi(su) + bias[sub * 2 + 1];
  int j = beg;
  for (; j + 8 <= end; j += 8) {
    int2 e[8];
    unsigned int hv[8];
#pragma unroll
    for (int u = 0; u < 8; ++u) e[u] = epack[j + u];
#pragma unroll
    for (int u = 0; u < 8; ++u) hv[u] = h32[(size_t)e[u].x * 32 + sub];
#pragma unroll
    for (int u = 0; u < 8; ++u) {
      float wn = __int_as_float(e[u].y);
      acc0 = fmaf(wn, bf_lo(hv[u]), acc0);
      acc1 = fmaf(wn, bf_hi(hv[u]), acc1);
    }
  }
  for (; j < end; ++j) {
    int2 e0 = epack[j];
    unsigned int hu = h32[(size_t)e0.x * 32 + sub];
    float wn = __int_as_float(e0.y);
    acc0 = fmaf(wn, bf_lo(hu), acc0);
    acc1 = fmaf(wn, bf_hi(hu), acc1);
  }
  float2* o2 = (float2*)out;
  if (RELU_NORM) {
    float v0 = fmaxf(acc0, 0.f);
    float v1 = fmaxf(acc1, 0.f);
    float ss = v0 * v0 + v1 * v1;
#pragma unroll
    for (int off = 16; off; off >>= 1) ss += __shfl_xor(ss, off, 64);  // within 32-half
    float inv = 1.f / fmaxf(sqrtf(ss), 1e-12f);
    o2[(size_t)node * 32 + sub] = make_float2(v0 * inv, v1 * inv);
  } else {
    o2[(size_t)node * 32 + sub] = make_float2(acc0, acc1);
  }
}

// ---------- atomic fallback path (fp32; only if ws too small for CSR) ----------

__global__ void init_agg_kernel(const float* __restrict__ dinv, const float* __restrict__ h,
                                const float* __restrict__ bias, float* __restrict__ out, int N) {
  int t = blockIdx.x * blockDim.x + threadIdx.x;
  int i = t >> 6, f = t & 63;
  if (i >= N) return;
  float di = dinv[i];
  out[t] = di * di * h[t] + bias[f];
}

__global__ void edge_atomic_kernel(const int* __restrict__ src, const int* __restrict__ dst,
                                   const float* __restrict__ dinv, const float* __restrict__ h,
                                   float* __restrict__ out, int E) {
  int t = blockIdx.x * blockDim.x + threadIdx.x;
  int e = t >> 6;
  if (e >= E) return;
  int f = t & 63;
  int s = src[e], d = dst[e];
  atomicAdd(&out[(size_t)d * HID + f], dinv[s] * dinv[d] * h[(size_t)s * HID + f]);
}

__global__ void relu_norm_kernel(float* __restrict__ hbuf, int N) {
  int t = blockIdx.x * blockDim.x + threadIdx.x;
  int i = t >> 6;
  if (i >= N) return;
  float v = fmaxf(hbuf[t], 0.f);
  float ss = v * v;
#pragma unroll
  for (int off = 32; off; off >>= 1) ss += __shfl_xor(ss, off, 64);
  hbuf[t] = v / fmaxf(sqrtf(ss), 1e-12f);
}

// ---------- host ----------

extern "C" void kernel_launch(void* const* d_in, const int* in_sizes, int n_in,
                              void* d_out, int out_size, void* d_ws, size_t ws_size,
                              hipStream_t stream) {
  const float* x  = (const float*)d_in[0];
  const int*   ei = (const int*)d_in[1];
  const float* W1 = (const float*)d_in[2];
  const float* b1 = (const float*)d_in[3];
  const float* W2 = (const float*)d_in[4];
  const float* b2 = (const float*)d_in[5];
  const float* W3 = (const float*)d_in[6];
  const float* b3 = (const float*)d_in[7];
  float* out = (float*)d_out;

  const int IN = in_sizes[2] / HID;   // 256
  const int N  = in_sizes[0] / IN;    // 100000
  const int E  = in_sizes[1] / 2;     // 1600000
  const int* srcI = ei;
  const int* dstI = ei + E;

  char* w = (char*)d_ws;
  size_t off = 0;
  auto alloc = [&](size_t bytes) { void* p = w + off; off = align256(off + bytes); return p; };
  float* A      = (float*)alloc((size_t)N * HID * 4);  // fp32 fallback / bf16 gather buffer
  float* dinv   = (float*)alloc((size_t)N * 4);
  int*   cnt    = (int*)alloc((size_t)N * 4);
  size_t base_need = off;
  int*   rowptr = (int*)alloc((size_t)(N + 1) * 4);
  int*   cursor = (int*)alloc((size_t)N * 4);
  int*   bsum   = (int*)alloc(1024 * 4);
  int*   boff   = (int*)alloc(1024 * 4);
  int2*  epack  = (int2*)alloc((size_t)E * 8);
  size_t csr_need = off;

  if (base_need > ws_size) return;
  const bool use_csr = (csr_need <= ws_size);
  __hip_bfloat16* Ab = (__hip_bfloat16*)A;
  unsigned int* Ab32 = (unsigned int*)A;

  const int blkE    = (E + 255) / 256;
  const int blkN    = (N + 255) / 256;
  const int blkScan = (N + 1023) / 1024;
  const int blkRow  = (N + 63) / 64;
  const int blkWave = (N * 64 + 255) / 256;
  const int blkAgg  = ((size_t)((N + 1) / 2) * 64 + 255) / 256;  // 2 nodes/wave
  const int blkEF   = ((size_t)E * 64 + 255) / 256;

  hipMemsetAsync(cnt, 0, (size_t)N * 4, stream);
  count_dst_kernel<<<blkE, 256, 0, stream>>>(dstI, cnt, E);
  dinv_kernel<<<blkN, 256, 0, stream>>>(cnt, dinv, N);

  if (use_csr) {
    scan_local_kernel<<<blkScan, 1024, 0, stream>>>(cnt, rowptr, bsum, N);
    scan_bsum_kernel<<<1, 1024, 0, stream>>>(bsum, boff, rowptr + N, blkScan);
    scan_add_kernel<<<blkN, 256, 0, stream>>>(boff, rowptr, cursor, N);
    scatter_kernel<<<blkE, 256, 0, stream>>>(srcI, dstI, dinv, cursor, epack, E);

    gemm_kernel<256><<<blkRow, 256, 0, stream>>>(x, W1, Ab, N);
    agg_kernel<true><<<blkAgg, 256, 0, stream>>>(rowptr, epack, dinv, Ab32, b1, out, N);
    gemm_kernel<64><<<blkRow, 256, 0, stream>>>(out, W2, Ab, N);
    agg_kernel<true><<<blkAgg, 256, 0, stream>>>(rowptr, epack, dinv, Ab32, b2, out, N);
    gemm_kernel<64><<<blkRow, 256, 0, stream>>>(out, W3, Ab, N);
    agg_kernel<false><<<blkAgg, 256, 0, stream>>>(rowptr, epack, dinv, Ab32, b3, out, N);
  } else {
    gemm_kernel<256><<<blkRow, 256, 0, stream>>>(x, W1, A, N);
    init_agg_kernel<<<blkWave, 256, 0, stream>>>(dinv, A, b1, out, N);
    edge_atomic_kernel<<<blkEF, 256, 0, stream>>>(srcI, dstI, dinv, A, out, E);
    relu_norm_kernel<<<blkWave, 256, 0, stream>>>(out, N);

    gemm_kernel<64><<<blkRow, 256, 0, stream>>>(out, W2, A, N);
    init_agg_kernel<<<blkWave, 256, 0, stream>>>(dinv, A, b2, out, N);
    edge_atomic_kernel<<<blkEF, 256, 0, stream>>>(srcI, dstI, dinv, A, out, E);
    relu_norm_kernel<<<blkWave, 256, 0, stream>>>(out, N);

    gemm_kernel<64><<<blkRow, 256, 0, stream>>>(out, W3, A, N);
    init_agg_kernel<<<blkWave, 256, 0, stream>>>(dinv, A, b3, out, N);
    edge_atomic_kernel<<<blkEF, 256, 0, stream>>>(srcI, dstI, dinv, A, out, E);
  }
}